// Round 1
// baseline (651.069 us; speedup 1.0000x reference)
//
#include <hip/hip_runtime.h>
#include <stdint.h>

// ---------------------------------------------------------------------------
// Causal self-attention, MI355X bf16-MFMA implementation.
//   x[4,2048,1024] fp32; wq/wk/wv/wo [1024,1024] fp32 (nn.Linear: y = x @ W.T)
// Pipeline:
//   1. cast x, weights -> bf16 in d_ws
//   2. gemm_bt bf16: Q = x@wq.T, K = x@wk.T, V = x@wv.T   (bf16 out, [8192,1024])
//   3. flash attention per (b,h,64q-tile), bf16 MFMA, fp32 online softmax
//   4. gemm_bt: out = O @ wo.T (fp32 out)
// ---------------------------------------------------------------------------

typedef __attribute__((ext_vector_type(8))) short bf16x8;   // 8 bf16 in 4 VGPRs
typedef __attribute__((ext_vector_type(4))) float f32x4;

#define GL2LDS16(g, l)                                                          \
  __builtin_amdgcn_global_load_lds(                                             \
      (const __attribute__((address_space(1))) unsigned int*)(g),               \
      (__attribute__((address_space(3))) unsigned int*)(l), 16, 0, 0)

__device__ inline unsigned short f2bf(float f) {
  union { float f; unsigned int u; } v; v.f = f;
  unsigned int u = v.u;
  u += 0x7FFFu + ((u >> 16) & 1u);    // round-to-nearest-even
  return (unsigned short)(u >> 16);
}

// ---------------------------- cast fp32 -> bf16 ----------------------------
__global__ void cast_f32_bf16(const float* __restrict__ in,
                              unsigned short* __restrict__ out, int n) {
  int i = (blockIdx.x * blockDim.x + threadIdx.x) * 8;
  if (i >= n) return;
  float4 a = *reinterpret_cast<const float4*>(in + i);
  float4 b = *reinterpret_cast<const float4*>(in + i + 4);
  union { unsigned short u[8]; uint4 v; } o;
  o.u[0] = f2bf(a.x); o.u[1] = f2bf(a.y); o.u[2] = f2bf(a.z); o.u[3] = f2bf(a.w);
  o.u[4] = f2bf(b.x); o.u[5] = f2bf(b.y); o.u[6] = f2bf(b.z); o.u[7] = f2bf(b.w);
  *reinterpret_cast<uint4*>(out + i) = o.v;
}

// ------------------------------- GEMM (B^T) --------------------------------
// C[m][n] = sum_k A[m][k] * Bw[n][k];  A:[M][K] bf16, Bw:[N][K] bf16.
// 128x128 tile, BK=32, 256 threads = 4 waves in 2x2, each wave 64x64 via
// 4x4 grid of 16x16x32 bf16 MFMA. global_load_lds width-16 staging (m97).
template <int OUT_BF16>
__global__ __launch_bounds__(256, 2) void gemm_bt(
    const unsigned short* __restrict__ A, const unsigned short* __restrict__ Bw,
    void* __restrict__ Cv, int M, int N, int K) {
  __shared__ __align__(16) unsigned short Al[128 * 32];
  __shared__ __align__(16) unsigned short Bl[128 * 32];
  const int tid = threadIdx.x;
  const int lane = tid & 63;
  const int w = tid >> 6;
  const int quad = lane >> 4;
  const int l16 = lane & 15;
  const int m0 = blockIdx.y * 128;
  const int n0 = blockIdx.x * 128;
  const int wm = w >> 1, wn = w & 1;
  const int arow = lane >> 2;          // 16 rows per wave-call
  const int acol = (lane & 3) * 8;     // 8 bf16 = 16B per lane
  f32x4 acc[4][4] = {};

  for (int k0 = 0; k0 < K; k0 += 32) {
    __syncthreads();
    for (int c = 0; c < 2; ++c) {
      int chunk = 2 * w + c;
      int ldsoff = __builtin_amdgcn_readfirstlane(chunk * 512);
      GL2LDS16(A + (size_t)(m0 + chunk * 16 + arow) * K + k0 + acol, &Al[ldsoff]);
      GL2LDS16(Bw + (size_t)(n0 + chunk * 16 + arow) * K + k0 + acol, &Bl[ldsoff]);
    }
    __syncthreads();
    bf16x8 af[4], bfr[4];
#pragma unroll
    for (int mi = 0; mi < 4; ++mi)
      af[mi] = *reinterpret_cast<const bf16x8*>(&Al[(wm * 64 + mi * 16 + l16) * 32 + quad * 8]);
#pragma unroll
    for (int ni = 0; ni < 4; ++ni)
      bfr[ni] = *reinterpret_cast<const bf16x8*>(&Bl[(wn * 64 + ni * 16 + l16) * 32 + quad * 8]);
#pragma unroll
    for (int mi = 0; mi < 4; ++mi)
#pragma unroll
      for (int ni = 0; ni < 4; ++ni)
        acc[mi][ni] = __builtin_amdgcn_mfma_f32_16x16x32_bf16(af[mi], bfr[ni], acc[mi][ni], 0, 0, 0);
  }

  // epilogue: D[row=quad*4+r][col=l16]  (verified m89/m91 C/D layout)
#pragma unroll
  for (int mi = 0; mi < 4; ++mi)
#pragma unroll
    for (int ni = 0; ni < 4; ++ni)
#pragma unroll
      for (int r = 0; r < 4; ++r) {
        int row = m0 + wm * 64 + mi * 16 + quad * 4 + r;
        int col = n0 + wn * 64 + ni * 16 + l16;
        if (OUT_BF16)
          ((unsigned short*)Cv)[(size_t)row * N + col] = f2bf(acc[mi][ni][r]);
        else
          ((float*)Cv)[(size_t)row * N + col] = acc[mi][ni][r];
      }
}

// ---------------------------- flash attention ------------------------------
// grid = B*H*(T/64) blocks, 256 threads. Wave w: 16 queries q0+16w..+15.
// K-tile = 32 keys. Q,K,V,O all [B*T][1024] bf16, head h at col h*64.
#define LOG2E 1.4426950408889634f

__global__ __launch_bounds__(256, 2) void attn(
    const unsigned short* __restrict__ Q, const unsigned short* __restrict__ Kg,
    const unsigned short* __restrict__ Vg, unsigned short* __restrict__ O) {
  __shared__ __align__(16) unsigned short Kl[32 * 64];   // [key][d]
  __shared__ __align__(16) unsigned short Vt[64 * 32];   // [d][key]
  __shared__ __align__(16) unsigned short Pl[4][16 * 32];// per-wave P tile
  const int bid = blockIdx.x;
  const int qt = bid & 31;          // T/64 = 32
  const int h = (bid >> 5) & 15;
  const int b = bid >> 9;
  const int q0 = qt * 64;
  const int tid = threadIdx.x, lane = tid & 63, w = tid >> 6;
  const int quad = lane >> 4, l16 = lane & 15;
  const size_t baserow = (size_t)b * 2048;
  const int colh = h * 64;

  // Q fragments (A-operand: Q[m=l16][k=quad*8+j], two 32-wide d chunks)
  const int qrow = q0 + w * 16 + l16;
  bf16x8 qf0 = *reinterpret_cast<const bf16x8*>(&Q[(baserow + qrow) * 1024 + colh + quad * 8]);
  bf16x8 qf1 = *reinterpret_cast<const bf16x8*>(&Q[(baserow + qrow) * 1024 + colh + 32 + quad * 8]);

  f32x4 o_acc[4] = {};
  float m_i[4], l_i[4];
#pragma unroll
  for (int r = 0; r < 4; ++r) { m_i[r] = -1e30f; l_i[r] = 0.f; }

  const int ntiles = q0 / 32 + 2;
  const int kv_off = __builtin_amdgcn_readfirstlane(w * 512);

  for (int kt = 0; kt < ntiles; ++kt) {
    __syncthreads();   // previous iteration's LDS readers done
    // stage K tile [32][64] via global_load_lds (wave w covers keys 8w..8w+7)
    {
      int r = w * 8 + (lane >> 3);
      int c = (lane & 7) * 8;
      GL2LDS16(Kg + (baserow + kt * 32 + r) * 1024 + colh + c, &Kl[kv_off]);
    }
    // stage V transposed [d][key]
    {
      int r = tid >> 3;
      int c0 = (tid & 7) * 8;
      uint4 raw = *reinterpret_cast<const uint4*>(&Vg[(baserow + kt * 32 + r) * 1024 + colh + c0]);
      unsigned short tmp[8];
      *reinterpret_cast<uint4*>(tmp) = raw;
#pragma unroll
      for (int j = 0; j < 8; ++j) Vt[(c0 + j) * 32 + r] = tmp[j];
    }
    __syncthreads();
    if (kt * 32 > q0 + w * 16 + 15) continue;  // wave fully masked (barriers above)

    // S = Q K^T : two 16-key halves, each 2 MFMAs over d
    f32x4 s[2] = {};
#pragma unroll
    for (int hk = 0; hk < 2; ++hk) {
      bf16x8 kf0 = *reinterpret_cast<const bf16x8*>(&Kl[(hk * 16 + l16) * 64 + quad * 8]);
      bf16x8 kf1 = *reinterpret_cast<const bf16x8*>(&Kl[(hk * 16 + l16) * 64 + 32 + quad * 8]);
      s[hk] = __builtin_amdgcn_mfma_f32_16x16x32_bf16(qf0, kf0, s[hk], 0, 0, 0);
      s[hk] = __builtin_amdgcn_mfma_f32_16x16x32_bf16(qf1, kf1, s[hk], 0, 0, 0);
    }

    // scale + causal mask + online softmax (rows = quad*4+r, cols = l16)
    float p0[4], p1[4], alpha[4];
#pragma unroll
    for (int r = 0; r < 4; ++r) {
      float s0 = s[0][r] * 0.125f;
      float s1 = s[1][r] * 0.125f;
      int qg = q0 + w * 16 + quad * 4 + r;
      int kg = kt * 32 + l16;
      if (kg > qg) s0 = -1e30f;
      if (kg + 16 > qg) s1 = -1e30f;
      p0[r] = s0; p1[r] = s1;
      float mx = fmaxf(s0, s1);
#pragma unroll
      for (int off = 1; off < 16; off <<= 1) mx = fmaxf(mx, __shfl_xor(mx, off));
      float mnew = fmaxf(m_i[r], mx);
      alpha[r] = exp2f((m_i[r] - mnew) * LOG2E);
      m_i[r] = mnew;
      float e0 = exp2f((s0 - mnew) * LOG2E);
      float e1 = exp2f((s1 - mnew) * LOG2E);
      p0[r] = e0; p1[r] = e1;
      float rs = e0 + e1;
#pragma unroll
      for (int off = 1; off < 16; off <<= 1) rs += __shfl_xor(rs, off);
      l_i[r] = l_i[r] * alpha[r] + rs;
    }
#pragma unroll
    for (int dt = 0; dt < 4; ++dt)
#pragma unroll
      for (int r = 0; r < 4; ++r) o_acc[dt][r] *= alpha[r];

    // P: C/D layout -> LDS -> A-operand layout (m120 round-trip)
#pragma unroll
    for (int r = 0; r < 4; ++r) {
      Pl[w][(quad * 4 + r) * 32 + l16] = f2bf(p0[r]);
      Pl[w][(quad * 4 + r) * 32 + 16 + l16] = f2bf(p1[r]);
    }
    asm volatile("s_waitcnt lgkmcnt(0)" ::: "memory");  // wave-local LDS RAW
    bf16x8 pf = *reinterpret_cast<const bf16x8*>(&Pl[w][l16 * 32 + quad * 8]);
#pragma unroll
    for (int dt = 0; dt < 4; ++dt) {
      bf16x8 vf = *reinterpret_cast<const bf16x8*>(&Vt[(dt * 16 + l16) * 32 + quad * 8]);
      o_acc[dt] = __builtin_amdgcn_mfma_f32_16x16x32_bf16(pf, vf, o_acc[dt], 0, 0, 0);
    }
  }

  // epilogue: O[b*T + q][h*64 + d] bf16
#pragma unroll
  for (int dt = 0; dt < 4; ++dt)
#pragma unroll
    for (int r = 0; r < 4; ++r) {
      int row = q0 + w * 16 + quad * 4 + r;
      O[(baserow + row) * 1024 + colh + dt * 16 + l16] = f2bf(o_acc[dt][r] / l_i[r]);
    }
}

// ------------------------------- launcher ----------------------------------
extern "C" void kernel_launch(void* const* d_in, const int* in_sizes, int n_in,
                              void* d_out, int out_size, void* d_ws, size_t ws_size,
                              hipStream_t stream) {
  const float* x = (const float*)d_in[0];
  const float* wq = (const float*)d_in[1];
  const float* wk = (const float*)d_in[2];
  const float* wv = (const float*)d_in[3];
  const float* wo = (const float*)d_in[4];

  const int BT = 4 * 2048;       // 8192 rows
  const int E = 1024;
  const size_t NX = (size_t)BT * E;      // 8M
  const size_t NW = (size_t)E * E;       // 1M

  unsigned short* xb = (unsigned short*)d_ws;
  unsigned short* wqb = xb + NX;
  unsigned short* wkb = wqb + NW;
  unsigned short* wvb = wkb + NW;
  unsigned short* wob = wvb + NW;
  unsigned short* Qb = wob + NW;
  unsigned short* Kb = Qb + NX;
  unsigned short* Vb = Kb + NX;
  unsigned short* Ob = Vb + NX;          // total ~88 MB of d_ws

  cast_f32_bf16<<<(int)(NX / 8 / 256), 256, 0, stream>>>(x, xb, (int)NX);
  cast_f32_bf16<<<(int)(NW / 8 / 256), 256, 0, stream>>>(wq, wqb, (int)NW);
  cast_f32_bf16<<<(int)(NW / 8 / 256), 256, 0, stream>>>(wk, wkb, (int)NW);
  cast_f32_bf16<<<(int)(NW / 8 / 256), 256, 0, stream>>>(wv, wvb, (int)NW);
  cast_f32_bf16<<<(int)(NW / 8 / 256), 256, 0, stream>>>(wo, wob, (int)NW);

  dim3 grid(E / 128, BT / 128);  // (8, 64)
  gemm_bt<1><<<grid, 256, 0, stream>>>(xb, wqb, Qb, BT, E, E);
  gemm_bt<1><<<grid, 256, 0, stream>>>(xb, wkb, Kb, BT, E, E);
  gemm_bt<1><<<grid, 256, 0, stream>>>(xb, wvb, Vb, BT, E, E);

  attn<<<4 * 16 * 32, 256, 0, stream>>>(Qb, Kb, Vb, Ob);

  gemm_bt<0><<<grid, 256, 0, stream>>>(Ob, wob, (float*)d_out, BT, E, E);
}

// Round 2
// 342.942 us; speedup vs baseline: 1.8985x; 1.8985x over previous
//
#include <hip/hip_runtime.h>
#include <stdint.h>

// ---------------------------------------------------------------------------
// Causal self-attention, MI355X bf16-MFMA, round 2.
//   1. cast x -> bf16; cast wq|wk|wv|wo -> one contiguous bf16 buffer
//   2. one gemm_bt: QKV[8192][3072] = x @ [wq|wk|wv].T   (bf16)
//   3. transpose_v: V -> Vt[bh][d][2048] with per-64 key permutation sigma
//   4. attn: 128q x 64k tiles, fixed-max softmax, XOR-swizzled LDS
//   5. gemm_bt: out = O @ wo.T (fp32)
// ---------------------------------------------------------------------------

typedef __attribute__((ext_vector_type(8))) short bf16x8;
typedef __attribute__((ext_vector_type(4))) float f32x4;
typedef unsigned short us;

#define GL2LDS16(g, l)                                                          \
  __builtin_amdgcn_global_load_lds(                                             \
      (const __attribute__((address_space(1))) unsigned int*)(g),               \
      (__attribute__((address_space(3))) unsigned int*)(l), 16, 0, 0)

__device__ inline us f2bf(float f) {
  union { float f; unsigned int u; } v; v.f = f;
  unsigned int u = v.u;
  u += 0x7FFFu + ((u >> 16) & 1u);
  return (us)(u >> 16);
}

// ---------------------------- casts ----------------------------------------
__global__ void cast_f32_bf16(const float* __restrict__ in,
                              us* __restrict__ out, int n) {
  int i = (blockIdx.x * blockDim.x + threadIdx.x) * 8;
  if (i >= n) return;
  float4 a = *reinterpret_cast<const float4*>(in + i);
  float4 b = *reinterpret_cast<const float4*>(in + i + 4);
  union { us u[8]; uint4 v; } o;
  o.u[0] = f2bf(a.x); o.u[1] = f2bf(a.y); o.u[2] = f2bf(a.z); o.u[3] = f2bf(a.w);
  o.u[4] = f2bf(b.x); o.u[5] = f2bf(b.y); o.u[6] = f2bf(b.z); o.u[7] = f2bf(b.w);
  *reinterpret_cast<uint4*>(out + i) = o.v;
}

// 4 weight matrices (1M elems each) -> contiguous bf16 [wq|wk|wv|wo]
__global__ void cast4_w(const float* __restrict__ w0, const float* __restrict__ w1,
                        const float* __restrict__ w2, const float* __restrict__ w3,
                        us* __restrict__ out) {
  int i = (blockIdx.x * blockDim.x + threadIdx.x) * 8;
  int seg = i >> 20;
  const float* s = (seg == 0) ? w0 : (seg == 1) ? w1 : (seg == 2) ? w2 : w3;
  int off = i & ((1 << 20) - 1);
  float4 a = *reinterpret_cast<const float4*>(s + off);
  float4 b = *reinterpret_cast<const float4*>(s + off + 4);
  union { us u[8]; uint4 v; } o;
  o.u[0] = f2bf(a.x); o.u[1] = f2bf(a.y); o.u[2] = f2bf(a.z); o.u[3] = f2bf(a.w);
  o.u[4] = f2bf(b.x); o.u[5] = f2bf(b.y); o.u[6] = f2bf(b.z); o.u[7] = f2bf(b.w);
  *reinterpret_cast<uint4*>(out + i) = o.v;
}

// ------------------------------- GEMM (B^T) --------------------------------
template <int OUT_BF16>
__global__ __launch_bounds__(256, 2) void gemm_bt(
    const us* __restrict__ A, const us* __restrict__ Bw,
    void* __restrict__ Cv, int M, int N, int K) {
  __shared__ __align__(16) us Al[128 * 32];
  __shared__ __align__(16) us Bl[128 * 32];
  const int tid = threadIdx.x;
  const int lane = tid & 63;
  const int w = tid >> 6;
  const int quad = lane >> 4;
  const int l16 = lane & 15;
  const int m0 = blockIdx.y * 128;
  const int n0 = blockIdx.x * 128;
  const int wm = w >> 1, wn = w & 1;
  const int arow = lane >> 2;
  const int acol = (lane & 3) * 8;
  f32x4 acc[4][4] = {};

  for (int k0 = 0; k0 < K; k0 += 32) {
    __syncthreads();
    for (int c = 0; c < 2; ++c) {
      int chunk = 2 * w + c;
      int ldsoff = __builtin_amdgcn_readfirstlane(chunk * 512);
      GL2LDS16(A + (size_t)(m0 + chunk * 16 + arow) * K + k0 + acol, &Al[ldsoff]);
      GL2LDS16(Bw + (size_t)(n0 + chunk * 16 + arow) * K + k0 + acol, &Bl[ldsoff]);
    }
    __syncthreads();
    bf16x8 af[4], bfr[4];
#pragma unroll
    for (int mi = 0; mi < 4; ++mi)
      af[mi] = *reinterpret_cast<const bf16x8*>(&Al[(wm * 64 + mi * 16 + l16) * 32 + quad * 8]);
#pragma unroll
    for (int ni = 0; ni < 4; ++ni)
      bfr[ni] = *reinterpret_cast<const bf16x8*>(&Bl[(wn * 64 + ni * 16 + l16) * 32 + quad * 8]);
#pragma unroll
    for (int mi = 0; mi < 4; ++mi)
#pragma unroll
      for (int ni = 0; ni < 4; ++ni)
        acc[mi][ni] = __builtin_amdgcn_mfma_f32_16x16x32_bf16(af[mi], bfr[ni], acc[mi][ni], 0, 0, 0);
  }

#pragma unroll
  for (int mi = 0; mi < 4; ++mi)
#pragma unroll
    for (int ni = 0; ni < 4; ++ni)
#pragma unroll
      for (int r = 0; r < 4; ++r) {
        int row = m0 + wm * 64 + mi * 16 + quad * 4 + r;
        int col = n0 + wn * 64 + ni * 16 + l16;
        if (OUT_BF16)
          ((us*)Cv)[(size_t)row * N + col] = f2bf(acc[mi][ni][r]);
        else
          ((float*)Cv)[(size_t)row * N + col] = acc[mi][ni][r];
      }
}

// -------------------- V transpose: [t][d] -> [bh][d][T] --------------------
// Within each 64-key block, keys are permuted: sigma(j) = (j&15)*4 + (j>>4),
// matching the P-pack order in attn.
__global__ __launch_bounds__(256) void transpose_v(const us* __restrict__ QKV,
                                                   us* __restrict__ Vt) {
  __shared__ __align__(16) us lds[64 * 80];
  const int bid = blockIdx.x;
  const int kt = bid & 31;
  const int bh = bid >> 5;
  const int b = bh >> 4, h = bh & 15;
  const int tid = threadIdx.x;
#pragma unroll
  for (int it = 0; it < 2; ++it) {
    int u = it * 256 + tid;
    int j = u >> 3;
    int dc = (u & 7) * 8;
    uint4 raw = *reinterpret_cast<const uint4*>(
        &QKV[((size_t)(b * 2048 + kt * 64 + j)) * 3072 + 2048 + h * 64 + dc]);
    us tmp[8];
    *reinterpret_cast<uint4*>(tmp) = raw;
    int sj = (j & 15) * 4 + (j >> 4);
#pragma unroll
    for (int e = 0; e < 8; ++e) lds[(dc + e) * 80 + sj] = tmp[e];
  }
  __syncthreads();
  int d = tid >> 2, c = tid & 3;
  size_t orow = ((size_t)(bh * 64 + d)) * 2048 + kt * 64 + c * 16;
  *reinterpret_cast<uint4*>(&Vt[orow]) = *reinterpret_cast<const uint4*>(&lds[d * 80 + c * 16]);
  *reinterpret_cast<uint4*>(&Vt[orow + 8]) = *reinterpret_cast<const uint4*>(&lds[d * 80 + c * 16 + 8]);
}

// ---------------------------- flash attention ------------------------------
// Block: 128 queries of one (b,h). Wave w rows: qg*64 + w*16 + [0,16).
// K-tile: 64 keys. Fixed-max softmax (M=12): p = exp2(s*c1 + c0), exact.
// LDS rows are 128B with 16B-unit XOR swizzle (unit ^ (row&7)) -> 2-way max.
#define LOG2E 1.4426950408889634f

__global__ __launch_bounds__(256, 4) void attn(
    const us* __restrict__ QKV, const us* __restrict__ Vt,
    us* __restrict__ O) {
  __shared__ __align__(16) us Kl[64 * 64];
  __shared__ __align__(16) us Vl[64 * 64];
  __shared__ __align__(16) us Pl[4][32 * 64];
  const int bid = blockIdx.x;
  const int qt = bid & 15;
  const int h = (bid >> 4) & 15;
  const int b = bid >> 8;
  const int q0 = qt * 128;
  const int tid = threadIdx.x, lane = tid & 63, w = tid >> 6;
  const int quad = lane >> 4, l16 = lane & 15;
  const size_t rowbase = (size_t)b * 2048;
  const int qcol = h * 64;
  const int kcol = 1024 + h * 64;

  bf16x8 qf[2][2];
#pragma unroll
  for (int qg = 0; qg < 2; ++qg) {
    int qrow = q0 + qg * 64 + w * 16 + l16;
#pragma unroll
    for (int dc = 0; dc < 2; ++dc)
      qf[qg][dc] = *reinterpret_cast<const bf16x8*>(
          &QKV[(rowbase + qrow) * 3072 + qcol + dc * 32 + quad * 8]);
  }

  f32x4 oacc[2][4] = {};
  float lsum[2][4] = {};

  const int srow = lane >> 3;
  const int sunit = lane & 7;
  const int n_it = qt * 2 + 2;
  const float C1 = 0.125f * LOG2E;
  const float C0 = -12.0f * LOG2E;

  for (int kt = 0; kt < n_it; ++kt) {
    __syncthreads();
    // stage K [key][d] and V^T [d][key''] tiles, source-XOR-swizzled
#pragma unroll
    for (int c = 0; c < 2; ++c) {
      int rr = w * 16 + c * 8 + srow;
      int base = __builtin_amdgcn_readfirstlane((w * 16 + c * 8) * 64);
      int gu = sunit ^ (rr & 7);
      GL2LDS16(QKV + (rowbase + kt * 64 + rr) * 3072 + kcol + gu * 8, &Kl[base]);
      GL2LDS16(Vt + ((size_t)((b * 16 + h) * 64 + rr)) * 2048 + kt * 64 + gu * 8, &Vl[base]);
    }
    __syncthreads();

    // S = Q K^T : s[qg][t] covers rows qg*64+w*16+[0,16), keys t*16+[0,16)
    f32x4 s[2][4] = {};
#pragma unroll
    for (int t = 0; t < 4; ++t) {
      int krow = t * 16 + l16;
#pragma unroll
      for (int dc = 0; dc < 2; ++dc) {
        bf16x8 kf = *reinterpret_cast<const bf16x8*>(
            &Kl[krow * 64 + (((dc * 4 + quad) ^ (l16 & 7)) * 8)]);
        s[0][t] = __builtin_amdgcn_mfma_f32_16x16x32_bf16(qf[0][dc], kf, s[0][t], 0, 0, 0);
        s[1][t] = __builtin_amdgcn_mfma_f32_16x16x32_bf16(qf[1][dc], kf, s[1][t], 0, 0, 0);
      }
    }

    // fixed-max softmax + pack P (bf16 truncation) into swizzled LDS
#pragma unroll
    for (int qg = 0; qg < 2; ++qg) {
      float p[4][4];
      bool do_mask = (kt * 64 + 63) > (q0 + qg * 64 + w * 16);
      if (do_mask) {
#pragma unroll
        for (int t = 0; t < 4; ++t)
#pragma unroll
          for (int r = 0; r < 4; ++r) {
            float e = exp2f(fmaf(s[qg][t][r], C1, C0));
            int kg = kt * 64 + t * 16 + l16;
            int qgl = q0 + qg * 64 + w * 16 + quad * 4 + r;
            p[t][r] = (kg <= qgl) ? e : 0.f;
            lsum[qg][r] += p[t][r];
          }
      } else {
#pragma unroll
        for (int t = 0; t < 4; ++t)
#pragma unroll
          for (int r = 0; r < 4; ++r) {
            float e = exp2f(fmaf(s[qg][t][r], C1, C0));
            p[t][r] = e;
            lsum[qg][r] += e;
          }
      }
#pragma unroll
      for (int r = 0; r < 4; ++r) {
        int prow = qg * 16 + quad * 4 + r;
        uint2 val;
        val.x = __builtin_amdgcn_perm(__float_as_uint(p[1][r]), __float_as_uint(p[0][r]), 0x07060302u);
        val.y = __builtin_amdgcn_perm(__float_as_uint(p[3][r]), __float_as_uint(p[2][r]), 0x07060302u);
        char* dst = (char*)&Pl[w][0] + prow * 128 +
                    (((l16 >> 1) ^ (prow & 7)) * 16) + (l16 & 1) * 8;
        *reinterpret_cast<uint2*>(dst) = val;
      }
    }
    asm volatile("s_waitcnt lgkmcnt(0)" ::: "memory");  // wave-local P RAW

    // O += P V  (keys permuted by sigma on both sides)
#pragma unroll
    for (int kc = 0; kc < 2; ++kc) {
      bf16x8 pf[2];
#pragma unroll
      for (int qg = 0; qg < 2; ++qg) {
        int arow = qg * 16 + l16;
        pf[qg] = *reinterpret_cast<const bf16x8*>(
            (const char*)&Pl[w][0] + arow * 128 + (((kc * 4 + quad) ^ (l16 & 7)) * 16));
      }
#pragma unroll
      for (int dt = 0; dt < 4; ++dt) {
        bf16x8 vf = *reinterpret_cast<const bf16x8*>(
            &Vl[(dt * 16 + l16) * 64 + (((kc * 4 + quad) ^ (l16 & 7)) * 8)]);
        oacc[0][dt] = __builtin_amdgcn_mfma_f32_16x16x32_bf16(pf[0], vf, oacc[0][dt], 0, 0, 0);
        oacc[1][dt] = __builtin_amdgcn_mfma_f32_16x16x32_bf16(pf[1], vf, oacc[1][dt], 0, 0, 0);
      }
    }
  }

  // deferred row-sum reduce + normalize + store
  float inv[2][4];
#pragma unroll
  for (int qg = 0; qg < 2; ++qg)
#pragma unroll
    for (int r = 0; r < 4; ++r) {
      float v = lsum[qg][r];
      v += __shfl_xor(v, 1); v += __shfl_xor(v, 2);
      v += __shfl_xor(v, 4); v += __shfl_xor(v, 8);
      inv[qg][r] = 1.0f / v;
    }
#pragma unroll
  for (int qg = 0; qg < 2; ++qg)
#pragma unroll
    for (int dt = 0; dt < 4; ++dt)
#pragma unroll
      for (int r = 0; r < 4; ++r) {
        int row = q0 + qg * 64 + w * 16 + quad * 4 + r;
        O[(rowbase + row) * 1024 + qcol + dt * 16 + l16] = f2bf(oacc[qg][dt][r] * inv[qg][r]);
      }
}

// ------------------------------- launcher ----------------------------------
extern "C" void kernel_launch(void* const* d_in, const int* in_sizes, int n_in,
                              void* d_out, int out_size, void* d_ws, size_t ws_size,
                              hipStream_t stream) {
  const float* x = (const float*)d_in[0];
  const float* wq = (const float*)d_in[1];
  const float* wk = (const float*)d_in[2];
  const float* wv = (const float*)d_in[3];
  const float* wo = (const float*)d_in[4];

  const int BT = 8192, E = 1024;
  const size_t NX = (size_t)BT * E;          // 8.39M
  const size_t NW = (size_t)E * E;           // 1M

  us* xb = (us*)d_ws;               // [8192][1024]; later reused as O (bf16)
  us* wbuf = xb + NX;               // [4096][1024] = wq|wk|wv|wo
  us* QKV = wbuf + 4 * NW;          // [8192][3072]
  us* VtB = QKV + (size_t)BT * 3 * E; // [64][64][2048]
  us* Ob = xb;                      // alias: x is dead after QKV GEMM

  cast_f32_bf16<<<(int)(NX / 8 / 256), 256, 0, stream>>>(x, xb, (int)NX);
  cast4_w<<<(int)(4 * NW / 8 / 256), 256, 0, stream>>>(wq, wk, wv, wo, wbuf);

  gemm_bt<1><<<dim3(24, 64), 256, 0, stream>>>(xb, wbuf, QKV, BT, 3 * E, E);
  transpose_v<<<64 * 32, 256, 0, stream>>>(QKV, VtB);
  attn<<<4 * 16 * 16, 256, 0, stream>>>(QKV, VtB, Ob);
  gemm_bt<0><<<dim3(8, 64), 256, 0, stream>>>(Ob, wbuf + 3 * NW, (float*)d_out, BT, E, E);
}

// Round 3
// 272.105 us; speedup vs baseline: 2.3927x; 1.2603x over previous
//
#include <hip/hip_runtime.h>
#include <stdint.h>

// ---------------------------------------------------------------------------
// Causal self-attention, MI355X bf16-MFMA, round 3.
//   1. cast x -> bf16; cast wq|wk|wv|wo -> bf16 (wq pre-scaled by 1/8*log2e)
//   2. one gemm_bt: QKV[8192][3072] = x @ [wq|wk|wv].T   (bf16)
//   3. transpose_v: V -> Vt[bh][d][2048] with per-64 key permutation sigma
//   4. attn: paired query tiles (p,15-p) per block for uniform work,
//      shared 64-key K/V staging, fixed-offset softmax p=exp2(s)
//   5. gemm_bt: out = O @ wo.T (fp32)
// ---------------------------------------------------------------------------

typedef __attribute__((ext_vector_type(8))) short bf16x8;
typedef __attribute__((ext_vector_type(4))) float f32x4;
typedef unsigned short us;

#define LOG2E 1.4426950408889634f

#define GL2LDS16(g, l)                                                          \
  __builtin_amdgcn_global_load_lds(                                             \
      (const __attribute__((address_space(1))) unsigned int*)(g),               \
      (__attribute__((address_space(3))) unsigned int*)(l), 16, 0, 0)

__device__ inline us f2bf(float f) {
  union { float f; unsigned int u; } v; v.f = f;
  unsigned int u = v.u;
  u += 0x7FFFu + ((u >> 16) & 1u);
  return (us)(u >> 16);
}

// ---------------------------- casts ----------------------------------------
__global__ void cast_f32_bf16(const float* __restrict__ in,
                              us* __restrict__ out, int n) {
  int i = (blockIdx.x * blockDim.x + threadIdx.x) * 8;
  if (i >= n) return;
  float4 a = *reinterpret_cast<const float4*>(in + i);
  float4 b = *reinterpret_cast<const float4*>(in + i + 4);
  union { us u[8]; uint4 v; } o;
  o.u[0] = f2bf(a.x); o.u[1] = f2bf(a.y); o.u[2] = f2bf(a.z); o.u[3] = f2bf(a.w);
  o.u[4] = f2bf(b.x); o.u[5] = f2bf(b.y); o.u[6] = f2bf(b.z); o.u[7] = f2bf(b.w);
  *reinterpret_cast<uint4*>(out + i) = o.v;
}

// 4 weight matrices -> contiguous bf16 [wq|wk|wv|wo]; wq scaled by QS so that
// the attention softmax becomes p = exp2(q.k) directly.
__global__ void cast4_w(const float* __restrict__ w0, const float* __restrict__ w1,
                        const float* __restrict__ w2, const float* __restrict__ w3,
                        us* __restrict__ out) {
  int i = (blockIdx.x * blockDim.x + threadIdx.x) * 8;
  int seg = i >> 20;
  const float* s = (seg == 0) ? w0 : (seg == 1) ? w1 : (seg == 2) ? w2 : w3;
  float sc = (seg == 0) ? (0.125f * LOG2E) : 1.0f;
  int off = i & ((1 << 20) - 1);
  float4 a = *reinterpret_cast<const float4*>(s + off);
  float4 b = *reinterpret_cast<const float4*>(s + off + 4);
  union { us u[8]; uint4 v; } o;
  o.u[0] = f2bf(a.x * sc); o.u[1] = f2bf(a.y * sc);
  o.u[2] = f2bf(a.z * sc); o.u[3] = f2bf(a.w * sc);
  o.u[4] = f2bf(b.x * sc); o.u[5] = f2bf(b.y * sc);
  o.u[6] = f2bf(b.z * sc); o.u[7] = f2bf(b.w * sc);
  *reinterpret_cast<uint4*>(out + i) = o.v;
}

// ------------------------------- GEMM (B^T) --------------------------------
template <int OUT_BF16>
__global__ __launch_bounds__(256, 2) void gemm_bt(
    const us* __restrict__ A, const us* __restrict__ Bw,
    void* __restrict__ Cv, int M, int N, int K) {
  __shared__ __align__(16) us Al[128 * 32];
  __shared__ __align__(16) us Bl[128 * 32];
  const int tid = threadIdx.x;
  const int lane = tid & 63;
  const int w = tid >> 6;
  const int quad = lane >> 4;
  const int l16 = lane & 15;
  const int m0 = blockIdx.y * 128;
  const int n0 = blockIdx.x * 128;
  const int wm = w >> 1, wn = w & 1;
  const int arow = lane >> 2;
  const int acol = (lane & 3) * 8;
  f32x4 acc[4][4] = {};

  for (int k0 = 0; k0 < K; k0 += 32) {
    __syncthreads();
    for (int c = 0; c < 2; ++c) {
      int chunk = 2 * w + c;
      int ldsoff = __builtin_amdgcn_readfirstlane(chunk * 512);
      GL2LDS16(A + (size_t)(m0 + chunk * 16 + arow) * K + k0 + acol, &Al[ldsoff]);
      GL2LDS16(Bw + (size_t)(n0 + chunk * 16 + arow) * K + k0 + acol, &Bl[ldsoff]);
    }
    __syncthreads();
    bf16x8 af[4], bfr[4];
#pragma unroll
    for (int mi = 0; mi < 4; ++mi)
      af[mi] = *reinterpret_cast<const bf16x8*>(&Al[(wm * 64 + mi * 16 + l16) * 32 + quad * 8]);
#pragma unroll
    for (int ni = 0; ni < 4; ++ni)
      bfr[ni] = *reinterpret_cast<const bf16x8*>(&Bl[(wn * 64 + ni * 16 + l16) * 32 + quad * 8]);
#pragma unroll
    for (int mi = 0; mi < 4; ++mi)
#pragma unroll
      for (int ni = 0; ni < 4; ++ni)
        acc[mi][ni] = __builtin_amdgcn_mfma_f32_16x16x32_bf16(af[mi], bfr[ni], acc[mi][ni], 0, 0, 0);
  }

#pragma unroll
  for (int mi = 0; mi < 4; ++mi)
#pragma unroll
    for (int ni = 0; ni < 4; ++ni)
#pragma unroll
      for (int r = 0; r < 4; ++r) {
        int row = m0 + wm * 64 + mi * 16 + quad * 4 + r;
        int col = n0 + wn * 64 + ni * 16 + l16;
        if (OUT_BF16)
          ((us*)Cv)[(size_t)row * N + col] = f2bf(acc[mi][ni][r]);
        else
          ((float*)Cv)[(size_t)row * N + col] = acc[mi][ni][r];
      }
}

// -------------------- V transpose: [t][d] -> [bh][d][T] --------------------
__global__ __launch_bounds__(256) void transpose_v(const us* __restrict__ QKV,
                                                   us* __restrict__ Vt) {
  __shared__ __align__(16) us lds[64 * 80];
  const int bid = blockIdx.x;
  const int kt = bid & 31;
  const int bh = bid >> 5;
  const int b = bh >> 4, h = bh & 15;
  const int tid = threadIdx.x;
#pragma unroll
  for (int it = 0; it < 2; ++it) {
    int u = it * 256 + tid;
    int j = u >> 3;
    int dc = (u & 7) * 8;
    uint4 raw = *reinterpret_cast<const uint4*>(
        &QKV[((size_t)(b * 2048 + kt * 64 + j)) * 3072 + 2048 + h * 64 + dc]);
    us tmp[8];
    *reinterpret_cast<uint4*>(tmp) = raw;
    int sj = (j & 15) * 4 + (j >> 4);
#pragma unroll
    for (int e = 0; e < 8; ++e) lds[(dc + e) * 80 + sj] = tmp[e];
  }
  __syncthreads();
  int d = tid >> 2, c = tid & 3;
  size_t orow = ((size_t)(bh * 64 + d)) * 2048 + kt * 64 + c * 16;
  *reinterpret_cast<uint4*>(&Vt[orow]) = *reinterpret_cast<const uint4*>(&lds[d * 80 + c * 16]);
  *reinterpret_cast<uint4*>(&Vt[orow + 8]) = *reinterpret_cast<const uint4*>(&lds[d * 80 + c * 16 + 8]);
}

// ---------------------------- flash attention ------------------------------
// Block = pair of 128-query tiles (p, 15-p) of one (b,h) -> uniform 34
// compute-units per block. K-tile = 64 keys, shared by both tiles.
// Softmax: p = exp2(s) (scale folded into wq; offset cancels in the ratio).
__global__ __launch_bounds__(256, 2) void attn(
    const us* __restrict__ QKV, const us* __restrict__ Vt,
    us* __restrict__ O) {
  __shared__ __align__(16) us Kl[64 * 64];
  __shared__ __align__(16) us Vl[64 * 64];
  __shared__ __align__(16) us Pl[4][32 * 64];
  const int bid = blockIdx.x;
  const int pr = bid & 7;
  const int h = (bid >> 3) & 15;
  const int b = bid >> 7;
  const int qtA = pr, qtB = 15 - pr;
  const int q0A = qtA * 128, q0B = qtB * 128;
  const int tid = threadIdx.x, lane = tid & 63, w = tid >> 6;
  const int quad = lane >> 4, l16 = lane & 15;
  const size_t rowbase = (size_t)b * 2048;
  const int qcol = h * 64;
  const int kcol = 1024 + h * 64;

  bf16x8 qfA[2][2], qfB[2][2];
#pragma unroll
  for (int qg = 0; qg < 2; ++qg)
#pragma unroll
    for (int dc = 0; dc < 2; ++dc) {
      qfA[qg][dc] = *reinterpret_cast<const bf16x8*>(
          &QKV[(rowbase + q0A + qg * 64 + w * 16 + l16) * 3072 + qcol + dc * 32 + quad * 8]);
      qfB[qg][dc] = *reinterpret_cast<const bf16x8*>(
          &QKV[(rowbase + q0B + qg * 64 + w * 16 + l16) * 3072 + qcol + dc * 32 + quad * 8]);
    }

  f32x4 oaccA[2][4] = {}, oaccB[2][4] = {};
  float lsumA[2][4] = {}, lsumB[2][4] = {};

  const int srow = lane >> 3;
  const int sunit = lane & 7;
  const int nA = qtA * 2 + 2;
  const int nB = qtB * 2 + 2;

  // one K-tile step for one 128-query tile
  auto process = [&](int q0, bf16x8 (&qf)[2][2], f32x4 (&oacc)[2][4],
                     float (&lsum)[2][4], int kt) {
    f32x4 s[2][4] = {};
#pragma unroll
    for (int t = 0; t < 4; ++t) {
      int krow = t * 16 + l16;
#pragma unroll
      for (int dc = 0; dc < 2; ++dc) {
        bf16x8 kf = *reinterpret_cast<const bf16x8*>(
            &Kl[krow * 64 + (((dc * 4 + quad) ^ (l16 & 7)) * 8)]);
        s[0][t] = __builtin_amdgcn_mfma_f32_16x16x32_bf16(qf[0][dc], kf, s[0][t], 0, 0, 0);
        s[1][t] = __builtin_amdgcn_mfma_f32_16x16x32_bf16(qf[1][dc], kf, s[1][t], 0, 0, 0);
      }
    }
#pragma unroll
    for (int qg = 0; qg < 2; ++qg) {
      float p[4][4];
      bool do_mask = (kt * 64 + 63) > (q0 + qg * 64 + w * 16);
      if (do_mask) {
#pragma unroll
        for (int t = 0; t < 4; ++t)
#pragma unroll
          for (int r = 0; r < 4; ++r) {
            float e = exp2f(s[qg][t][r]);
            int kg = kt * 64 + t * 16 + l16;
            int qgl = q0 + qg * 64 + w * 16 + quad * 4 + r;
            p[t][r] = (kg <= qgl) ? e : 0.f;
            lsum[qg][r] += p[t][r];
          }
      } else {
#pragma unroll
        for (int t = 0; t < 4; ++t)
#pragma unroll
          for (int r = 0; r < 4; ++r) {
            float e = exp2f(s[qg][t][r]);
            p[t][r] = e;
            lsum[qg][r] += e;
          }
      }
#pragma unroll
      for (int r = 0; r < 4; ++r) {
        int prow = qg * 16 + quad * 4 + r;
        uint2 val;
        val.x = __builtin_amdgcn_perm(__float_as_uint(p[1][r]), __float_as_uint(p[0][r]), 0x07060302u);
        val.y = __builtin_amdgcn_perm(__float_as_uint(p[3][r]), __float_as_uint(p[2][r]), 0x07060302u);
        char* dst = (char*)&Pl[w][0] + prow * 128 +
                    (((l16 >> 1) ^ (prow & 7)) * 16) + (l16 & 1) * 8;
        *reinterpret_cast<uint2*>(dst) = val;
      }
    }
    asm volatile("s_waitcnt lgkmcnt(0)" ::: "memory");  // wave-local P RAW
#pragma unroll
    for (int kc = 0; kc < 2; ++kc) {
      bf16x8 pf[2];
#pragma unroll
      for (int qg = 0; qg < 2; ++qg)
        pf[qg] = *reinterpret_cast<const bf16x8*>(
            (const char*)&Pl[w][0] + (qg * 16 + l16) * 128 + (((kc * 4 + quad) ^ (l16 & 7)) * 16));
#pragma unroll
      for (int dt = 0; dt < 4; ++dt) {
        bf16x8 vf = *reinterpret_cast<const bf16x8*>(
            &Vl[(dt * 16 + l16) * 64 + (((kc * 4 + quad) ^ (l16 & 7)) * 8)]);
        oacc[0][dt] = __builtin_amdgcn_mfma_f32_16x16x32_bf16(pf[0], vf, oacc[0][dt], 0, 0, 0);
        oacc[1][dt] = __builtin_amdgcn_mfma_f32_16x16x32_bf16(pf[1], vf, oacc[1][dt], 0, 0, 0);
      }
    }
  };

  for (int kt = 0; kt < nB; ++kt) {
    __syncthreads();
#pragma unroll
    for (int c = 0; c < 2; ++c) {
      int rr = w * 16 + c * 8 + srow;
      int base = __builtin_amdgcn_readfirstlane((w * 16 + c * 8) * 64);
      int gu = sunit ^ (rr & 7);
      GL2LDS16(QKV + (rowbase + kt * 64 + rr) * 3072 + kcol + gu * 8, &Kl[base]);
      GL2LDS16(Vt + ((size_t)((b * 16 + h) * 64 + rr)) * 2048 + kt * 64 + gu * 8, &Vl[base]);
    }
    __syncthreads();
    process(q0B, qfB, oaccB, lsumB, kt);
    if (kt < nA) process(q0A, qfA, oaccA, lsumA, kt);
  }

  auto finalize = [&](int q0, f32x4 (&oacc)[2][4], float (&lsum)[2][4]) {
#pragma unroll
    for (int qg = 0; qg < 2; ++qg) {
      float inv[4];
#pragma unroll
      for (int r = 0; r < 4; ++r) {
        float v = lsum[qg][r];
        v += __shfl_xor(v, 1); v += __shfl_xor(v, 2);
        v += __shfl_xor(v, 4); v += __shfl_xor(v, 8);
        inv[r] = 1.0f / v;
      }
#pragma unroll
      for (int dt = 0; dt < 4; ++dt)
#pragma unroll
        for (int r = 0; r < 4; ++r) {
          int row = q0 + qg * 64 + w * 16 + quad * 4 + r;
          O[(rowbase + row) * 1024 + qcol + dt * 16 + l16] = f2bf(oacc[qg][dt][r] * inv[r]);
        }
    }
  };
  finalize(q0A, oaccA, lsumA);
  finalize(q0B, oaccB, lsumB);
}

// ------------------------------- launcher ----------------------------------
extern "C" void kernel_launch(void* const* d_in, const int* in_sizes, int n_in,
                              void* d_out, int out_size, void* d_ws, size_t ws_size,
                              hipStream_t stream) {
  const float* x = (const float*)d_in[0];
  const float* wq = (const float*)d_in[1];
  const float* wk = (const float*)d_in[2];
  const float* wv = (const float*)d_in[3];
  const float* wo = (const float*)d_in[4];

  const int BT = 8192, E = 1024;
  const size_t NX = (size_t)BT * E;
  const size_t NW = (size_t)E * E;

  us* xb = (us*)d_ws;                 // [8192][1024]; later reused as O
  us* wbuf = xb + NX;                 // wq|wk|wv|wo bf16
  us* QKV = wbuf + 4 * NW;            // [8192][3072]
  us* VtB = QKV + (size_t)BT * 3 * E; // [64 bh][64 d][2048]
  us* Ob = xb;

  cast_f32_bf16<<<(int)(NX / 8 / 256), 256, 0, stream>>>(x, xb, (int)NX);
  cast4_w<<<(int)(4 * NW / 8 / 256), 256, 0, stream>>>(wq, wk, wv, wo, wbuf);

  gemm_bt<1><<<dim3(24, 64), 256, 0, stream>>>(xb, wbuf, QKV, BT, 3 * E, E);
  transpose_v<<<64 * 32, 256, 0, stream>>>(QKV, VtB);
  attn<<<4 * 16 * 8, 256, 0, stream>>>(QKV, VtB, Ob);
  gemm_bt<0><<<dim3(8, 64), 256, 0, stream>>>(Ob, wbuf + 3 * NW, (float*)d_out, BT, E, E);
}

// Round 4
// 261.669 us; speedup vs baseline: 2.4881x; 1.0399x over previous
//
#include <hip/hip_runtime.h>
#include <stdint.h>

// ---------------------------------------------------------------------------
// Causal self-attention, MI355X bf16-MFMA, round 4.
//   1. cast_all: x -> bf16, wq|wk|wv|wo -> bf16 (wq pre-scaled by 1/8*log2e)
//   2. gemm_bt: QKV[8192][3072] = x @ [wq|wk|wv].T   (bf16)
//   3. transpose_v: V -> Vt[bh][d][2048] with per-64 key permutation sigma
//   4. attn: 512-thread blocks, paired 128q tiles (p,15-p), 64-key tiles,
//      each wave owns a 16-row strip; fixed-offset softmax p=exp2(s)
//   5. gemm_bt: out = O @ wo.T (fp32)
// ---------------------------------------------------------------------------

typedef __attribute__((ext_vector_type(8))) short bf16x8;
typedef __attribute__((ext_vector_type(4))) float f32x4;
typedef unsigned short us;

#define LOG2E 1.4426950408889634f

#define GL2LDS16(g, l)                                                          \
  __builtin_amdgcn_global_load_lds(                                             \
      (const __attribute__((address_space(1))) unsigned int*)(g),               \
      (__attribute__((address_space(3))) unsigned int*)(l), 16, 0, 0)

__device__ inline us f2bf(float f) {
  union { float f; unsigned int u; } v; v.f = f;
  unsigned int u = v.u;
  u += 0x7FFFu + ((u >> 16) & 1u);
  return (us)(u >> 16);
}

// ---------------------------- fused casts ----------------------------------
// region 0: x (8M elems) -> xb ; region 1: 4 weights (1M each) -> wbuf,
// wq scaled by 0.125*log2e so attention softmax is p = exp2(q.k).
__global__ void cast_all(const float* __restrict__ x,
                         const float* __restrict__ w0, const float* __restrict__ w1,
                         const float* __restrict__ w2, const float* __restrict__ w3,
                         us* __restrict__ xb, us* __restrict__ wbuf) {
  int i = (blockIdx.x * blockDim.x + threadIdx.x) * 8;
  const float* src;
  us* dst;
  float sc = 1.0f;
  if (i < (8 << 20)) {
    src = x + i; dst = xb + i;
  } else {
    int j = i - (8 << 20);
    int seg = j >> 20;
    int off = j & ((1 << 20) - 1);
    const float* w = (seg == 0) ? w0 : (seg == 1) ? w1 : (seg == 2) ? w2 : w3;
    if (seg == 0) sc = 0.125f * LOG2E;
    src = w + off; dst = wbuf + j;
  }
  float4 a = *reinterpret_cast<const float4*>(src);
  float4 b = *reinterpret_cast<const float4*>(src + 4);
  union { us u[8]; uint4 v; } o;
  o.u[0] = f2bf(a.x * sc); o.u[1] = f2bf(a.y * sc);
  o.u[2] = f2bf(a.z * sc); o.u[3] = f2bf(a.w * sc);
  o.u[4] = f2bf(b.x * sc); o.u[5] = f2bf(b.y * sc);
  o.u[6] = f2bf(b.z * sc); o.u[7] = f2bf(b.w * sc);
  *reinterpret_cast<uint4*>(dst) = o.v;
}

// ------------------------------- GEMM (B^T) --------------------------------
template <int OUT_BF16>
__global__ __launch_bounds__(256, 2) void gemm_bt(
    const us* __restrict__ A, const us* __restrict__ Bw,
    void* __restrict__ Cv, int M, int N, int K) {
  __shared__ __align__(16) us Al[128 * 32];
  __shared__ __align__(16) us Bl[128 * 32];
  const int tid = threadIdx.x;
  const int lane = tid & 63;
  const int w = tid >> 6;
  const int quad = lane >> 4;
  const int l16 = lane & 15;
  const int m0 = blockIdx.y * 128;
  const int n0 = blockIdx.x * 128;
  const int wm = w >> 1, wn = w & 1;
  const int arow = lane >> 2;
  const int acol = (lane & 3) * 8;
  f32x4 acc[4][4] = {};

  for (int k0 = 0; k0 < K; k0 += 32) {
    __syncthreads();
    for (int c = 0; c < 2; ++c) {
      int chunk = 2 * w + c;
      int ldsoff = __builtin_amdgcn_readfirstlane(chunk * 512);
      GL2LDS16(A + (size_t)(m0 + chunk * 16 + arow) * K + k0 + acol, &Al[ldsoff]);
      GL2LDS16(Bw + (size_t)(n0 + chunk * 16 + arow) * K + k0 + acol, &Bl[ldsoff]);
    }
    __syncthreads();
    bf16x8 af[4], bfr[4];
#pragma unroll
    for (int mi = 0; mi < 4; ++mi)
      af[mi] = *reinterpret_cast<const bf16x8*>(&Al[(wm * 64 + mi * 16 + l16) * 32 + quad * 8]);
#pragma unroll
    for (int ni = 0; ni < 4; ++ni)
      bfr[ni] = *reinterpret_cast<const bf16x8*>(&Bl[(wn * 64 + ni * 16 + l16) * 32 + quad * 8]);
#pragma unroll
    for (int mi = 0; mi < 4; ++mi)
#pragma unroll
      for (int ni = 0; ni < 4; ++ni)
        acc[mi][ni] = __builtin_amdgcn_mfma_f32_16x16x32_bf16(af[mi], bfr[ni], acc[mi][ni], 0, 0, 0);
  }

#pragma unroll
  for (int mi = 0; mi < 4; ++mi)
#pragma unroll
    for (int ni = 0; ni < 4; ++ni)
#pragma unroll
      for (int r = 0; r < 4; ++r) {
        int row = m0 + wm * 64 + mi * 16 + quad * 4 + r;
        int col = n0 + wn * 64 + ni * 16 + l16;
        if (OUT_BF16)
          ((us*)Cv)[(size_t)row * N + col] = f2bf(acc[mi][ni][r]);
        else
          ((float*)Cv)[(size_t)row * N + col] = acc[mi][ni][r];
      }
}

// -------------------- V transpose: [t][d] -> [bh][d][T] --------------------
// Per-64 key permutation: key j lands at sigma(j) = (j&15)*4 + (j>>4),
// matching the P-pack order in attn.
__global__ __launch_bounds__(256) void transpose_v(const us* __restrict__ QKV,
                                                   us* __restrict__ Vt) {
  __shared__ __align__(16) us lds[64 * 80];
  const int bid = blockIdx.x;
  const int kt = bid & 31;
  const int bh = bid >> 5;
  const int b = bh >> 4, h = bh & 15;
  const int tid = threadIdx.x;
#pragma unroll
  for (int it = 0; it < 2; ++it) {
    int u = it * 256 + tid;
    int j = u >> 3;
    int dc = (u & 7) * 8;
    uint4 raw = *reinterpret_cast<const uint4*>(
        &QKV[((size_t)(b * 2048 + kt * 64 + j)) * 3072 + 2048 + h * 64 + dc]);
    us tmp[8];
    *reinterpret_cast<uint4*>(tmp) = raw;
    int sj = (j & 15) * 4 + (j >> 4);
#pragma unroll
    for (int e = 0; e < 8; ++e) lds[(dc + e) * 80 + sj] = tmp[e];
  }
  __syncthreads();
  int d = tid >> 2, c = tid & 3;
  size_t orow = ((size_t)(bh * 64 + d)) * 2048 + kt * 64 + c * 16;
  *reinterpret_cast<uint4*>(&Vt[orow]) = *reinterpret_cast<const uint4*>(&lds[d * 80 + c * 16]);
  *reinterpret_cast<uint4*>(&Vt[orow + 8]) = *reinterpret_cast<const uint4*>(&lds[d * 80 + c * 16 + 8]);
}

// ---------------------------- flash attention ------------------------------
// Block = 512 threads (8 waves) working a pair of 128-query tiles (p, 15-p)
// of one (b,h); wave w owns query strip rows q0 + w*16 + [0,16) of each tile.
// K-tile = 64 keys shared by both tiles. Softmax p = exp2(s), scale folded
// into wq, fixed offset cancels in the P/lsum ratio. LDS XOR-swizzled.
__global__ __launch_bounds__(512, 4) void attn(
    const us* __restrict__ QKV, const us* __restrict__ Vt,
    us* __restrict__ O) {
  __shared__ __align__(16) us Kl[64 * 64];
  __shared__ __align__(16) us Vl[64 * 64];
  __shared__ __align__(16) us Pl[8][16 * 64];
  const int bid = blockIdx.x;
  const int pr = bid & 7;
  const int h = (bid >> 3) & 15;
  const int b = bid >> 7;
  const int q0A = pr * 128, q0B = (15 - pr) * 128;
  const int tid = threadIdx.x, lane = tid & 63, w = tid >> 6;   // w in [0,8)
  const int quad = lane >> 4, l16 = lane & 15;
  const size_t rowbase = (size_t)b * 2048;
  const int qcol = h * 64;
  const int kcol = 1024 + h * 64;

  bf16x8 qfA[2], qfB[2];
#pragma unroll
  for (int dc = 0; dc < 2; ++dc) {
    qfA[dc] = *reinterpret_cast<const bf16x8*>(
        &QKV[(rowbase + q0A + w * 16 + l16) * 3072 + qcol + dc * 32 + quad * 8]);
    qfB[dc] = *reinterpret_cast<const bf16x8*>(
        &QKV[(rowbase + q0B + w * 16 + l16) * 3072 + qcol + dc * 32 + quad * 8]);
  }

  f32x4 oaccA[4] = {}, oaccB[4] = {};
  float lsumA[4] = {}, lsumB[4] = {};

  // staging: thread tid loads 16B of row rr, source-XOR-swizzled
  const int rr = tid >> 3;          // 0..63
  const int gu = (tid & 7) ^ (rr & 7);
  const int base = __builtin_amdgcn_readfirstlane(w * 512);
  const int nB = 2 * (15 - pr) + 2;

  auto process = [&](int q0, bf16x8 (&qf)[2], f32x4 (&oacc)[4],
                     float (&lsum)[4], int kt) {
    f32x4 s[4] = {};
#pragma unroll
    for (int t = 0; t < 4; ++t) {
      int krow = t * 16 + l16;
#pragma unroll
      for (int dc = 0; dc < 2; ++dc) {
        bf16x8 kf = *reinterpret_cast<const bf16x8*>(
            &Kl[krow * 64 + (((dc * 4 + quad) ^ (l16 & 7)) * 8)]);
        s[t] = __builtin_amdgcn_mfma_f32_16x16x32_bf16(qf[dc], kf, s[t], 0, 0, 0);
      }
    }
    float p[4][4];
    bool do_mask = (kt * 64 + 63) > (q0 + w * 16);
    if (do_mask) {
#pragma unroll
      for (int t = 0; t < 4; ++t)
#pragma unroll
        for (int r = 0; r < 4; ++r) {
          float e = exp2f(s[t][r]);
          int kg = kt * 64 + t * 16 + l16;
          int qgl = q0 + w * 16 + quad * 4 + r;
          p[t][r] = (kg <= qgl) ? e : 0.f;
          lsum[r] += p[t][r];
        }
    } else {
#pragma unroll
      for (int t = 0; t < 4; ++t)
#pragma unroll
        for (int r = 0; r < 4; ++r) {
          float e = exp2f(s[t][r]);
          p[t][r] = e;
          lsum[r] += e;
        }
    }
#pragma unroll
    for (int r = 0; r < 4; ++r) {
      int prow = quad * 4 + r;
      uint2 val;
      val.x = __builtin_amdgcn_perm(__float_as_uint(p[1][r]), __float_as_uint(p[0][r]), 0x07060302u);
      val.y = __builtin_amdgcn_perm(__float_as_uint(p[3][r]), __float_as_uint(p[2][r]), 0x07060302u);
      char* dst = (char*)&Pl[w][0] + prow * 128 +
                  (((l16 >> 1) ^ (prow & 7)) * 16) + (l16 & 1) * 8;
      *reinterpret_cast<uint2*>(dst) = val;
    }
    asm volatile("s_waitcnt lgkmcnt(0)" ::: "memory");  // wave-local P RAW
#pragma unroll
    for (int kc = 0; kc < 2; ++kc) {
      bf16x8 pf = *reinterpret_cast<const bf16x8*>(
          (const char*)&Pl[w][0] + l16 * 128 + (((kc * 4 + quad) ^ (l16 & 7)) * 16));
#pragma unroll
      for (int dt = 0; dt < 4; ++dt) {
        bf16x8 vf = *reinterpret_cast<const bf16x8*>(
            &Vl[(dt * 16 + l16) * 64 + (((kc * 4 + quad) ^ (l16 & 7)) * 8)]);
        oacc[dt] = __builtin_amdgcn_mfma_f32_16x16x32_bf16(pf, vf, oacc[dt], 0, 0, 0);
      }
    }
  };

  for (int kt = 0; kt < nB; ++kt) {
    __syncthreads();
    GL2LDS16(QKV + (rowbase + kt * 64 + rr) * 3072 + kcol + gu * 8, &Kl[base]);
    GL2LDS16(Vt + ((size_t)((b * 16 + h) * 64 + rr)) * 2048 + kt * 64 + gu * 8, &Vl[base]);
    __syncthreads();
    if (kt * 64 <= q0B + w * 16 + 15) process(q0B, qfB, oaccB, lsumB, kt);
    if (kt * 64 <= q0A + w * 16 + 15) process(q0A, qfA, oaccA, lsumA, kt);
  }

  auto finalize = [&](int q0, f32x4 (&oacc)[4], float (&lsum)[4]) {
    float inv[4];
#pragma unroll
    for (int r = 0; r < 4; ++r) {
      float v = lsum[r];
      v += __shfl_xor(v, 1); v += __shfl_xor(v, 2);
      v += __shfl_xor(v, 4); v += __shfl_xor(v, 8);
      inv[r] = 1.0f / v;
    }
#pragma unroll
    for (int dt = 0; dt < 4; ++dt)
#pragma unroll
      for (int r = 0; r < 4; ++r) {
        int row = q0 + w * 16 + quad * 4 + r;
        O[(rowbase + row) * 1024 + qcol + dt * 16 + l16] = f2bf(oacc[dt][r] * inv[r]);
      }
  };
  finalize(q0A, oaccA, lsumA);
  finalize(q0B, oaccB, lsumB);
}

// ------------------------------- launcher ----------------------------------
extern "C" void kernel_launch(void* const* d_in, const int* in_sizes, int n_in,
                              void* d_out, int out_size, void* d_ws, size_t ws_size,
                              hipStream_t stream) {
  const float* x = (const float*)d_in[0];
  const float* wq = (const float*)d_in[1];
  const float* wk = (const float*)d_in[2];
  const float* wv = (const float*)d_in[3];
  const float* wo = (const float*)d_in[4];

  const int BT = 8192, E = 1024;
  const size_t NX = (size_t)BT * E;
  const size_t NW = (size_t)E * E;

  us* xb = (us*)d_ws;                 // [8192][1024]; later reused as O
  us* wbuf = xb + NX;                 // wq|wk|wv|wo bf16
  us* QKV = wbuf + 4 * NW;            // [8192][3072]
  us* VtB = QKV + (size_t)BT * 3 * E; // [64 bh][64 d][2048]
  us* Ob = xb;

  cast_all<<<(int)((NX + 4 * NW) / 8 / 256), 256, 0, stream>>>(x, wq, wk, wv, wo, xb, wbuf);

  gemm_bt<1><<<dim3(24, 64), 256, 0, stream>>>(xb, wbuf, QKV, BT, 3 * E, E);
  transpose_v<<<64 * 32, 256, 0, stream>>>(QKV, VtB);
  attn<<<4 * 16 * 8, 512, 0, stream>>>(QKV, VtB, Ob);
  gemm_bt<0><<<dim3(8, 64), 256, 0, stream>>>(Ob, wbuf + 3 * NW, (float*)d_out, BT, E, E);
}

// Round 5
// 239.260 us; speedup vs baseline: 2.7212x; 1.0937x over previous
//
#include <hip/hip_runtime.h>
#include <stdint.h>

// ---------------------------------------------------------------------------
// Causal self-attention, MI355X bf16-MFMA, round 5.
//   1. cast_all: x -> bf16, wq|wk|wv|wo -> bf16 (wq pre-scaled by 1/8*log2e)
//   2. gemm_bt (BK=64, XOR-swizzled LDS): QKV = x @ [wq|wk|wv].T   (bf16)
//   3. transpose_v: V -> Vt[bh][d][2048] with per-64 key permutation sigma
//   4. attn: 512-thread blocks, paired 128q tiles (p,15-p); v_exp_f32 softmax,
//      row-sum via MFMA against a ones-fragment (no VALU lsum, no shuffles)
//   5. gemm_bt: out = O @ wo.T (fp32)
// ---------------------------------------------------------------------------

typedef __attribute__((ext_vector_type(8))) short bf16x8;
typedef __attribute__((ext_vector_type(4))) float f32x4;
typedef unsigned short us;

#define LOG2E 1.4426950408889634f

#define GL2LDS16(g, l)                                                          \
  __builtin_amdgcn_global_load_lds(                                             \
      (const __attribute__((address_space(1))) unsigned int*)(g),               \
      (__attribute__((address_space(3))) unsigned int*)(l), 16, 0, 0)

__device__ inline us f2bf(float f) {
  union { float f; unsigned int u; } v; v.f = f;
  unsigned int u = v.u;
  u += 0x7FFFu + ((u >> 16) & 1u);
  return (us)(u >> 16);
}

// ---------------------------- fused casts ----------------------------------
__global__ void cast_all(const float* __restrict__ x,
                         const float* __restrict__ w0, const float* __restrict__ w1,
                         const float* __restrict__ w2, const float* __restrict__ w3,
                         us* __restrict__ xb, us* __restrict__ wbuf) {
  int i = (blockIdx.x * blockDim.x + threadIdx.x) * 8;
  const float* src;
  us* dst;
  float sc = 1.0f;
  if (i < (8 << 20)) {
    src = x + i; dst = xb + i;
  } else {
    int j = i - (8 << 20);
    int seg = j >> 20;
    int off = j & ((1 << 20) - 1);
    const float* w = (seg == 0) ? w0 : (seg == 1) ? w1 : (seg == 2) ? w2 : w3;
    if (seg == 0) sc = 0.125f * LOG2E;
    src = w + off; dst = wbuf + j;
  }
  float4 a = *reinterpret_cast<const float4*>(src);
  float4 b = *reinterpret_cast<const float4*>(src + 4);
  union { us u[8]; uint4 v; } o;
  o.u[0] = f2bf(a.x * sc); o.u[1] = f2bf(a.y * sc);
  o.u[2] = f2bf(a.z * sc); o.u[3] = f2bf(a.w * sc);
  o.u[4] = f2bf(b.x * sc); o.u[5] = f2bf(b.y * sc);
  o.u[6] = f2bf(b.z * sc); o.u[7] = f2bf(b.w * sc);
  *reinterpret_cast<uint4*>(dst) = o.v;
}

// ------------------------- GEMM (B^T), BK=64 -------------------------------
// 128x128 tile, BK=64 (32 MFMAs/wave per barrier), 64-elem LDS rows with
// 16B-unit XOR swizzle (unit ^ (row&7)) applied on the SOURCE index so
// global_load_lds staging + conflict-free ds_read_b128 compose.
template <int OUT_BF16>
__global__ __launch_bounds__(256, 2) void gemm_bt(
    const us* __restrict__ A, const us* __restrict__ Bw,
    void* __restrict__ Cv, int M, int N, int K) {
  __shared__ __align__(16) us Al[128 * 64];
  __shared__ __align__(16) us Bl[128 * 64];
  const int tid = threadIdx.x;
  const int lane = tid & 63;
  const int w = tid >> 6;
  const int quad = lane >> 4;
  const int l16 = lane & 15;
  const int m0 = blockIdx.y * 128;
  const int n0 = blockIdx.x * 128;
  const int wm = w >> 1, wn = w & 1;
  const int srow_base = w * 8 + (lane >> 3);   // + it*32
  const int sunit = lane & 7;
  f32x4 acc[4][4] = {};

  for (int k0 = 0; k0 < K; k0 += 64) {
    __syncthreads();
#pragma unroll
    for (int it = 0; it < 4; ++it) {
      int row = it * 32 + srow_base;
      int gu = sunit ^ (row & 7);
      int base = __builtin_amdgcn_readfirstlane((it * 256 + w * 64) * 8);
      GL2LDS16(A + (size_t)(m0 + row) * K + k0 + gu * 8, &Al[base]);
      GL2LDS16(Bw + (size_t)(n0 + row) * K + k0 + gu * 8, &Bl[base]);
    }
    __syncthreads();
#pragma unroll
    for (int kk = 0; kk < 2; ++kk) {
      bf16x8 af[4], bfr[4];
#pragma unroll
      for (int mi = 0; mi < 4; ++mi) {
        int row = wm * 64 + mi * 16 + l16;
        af[mi] = *reinterpret_cast<const bf16x8*>(
            &Al[row * 64 + (((kk * 4 + quad) ^ (row & 7)) * 8)]);
      }
#pragma unroll
      for (int ni = 0; ni < 4; ++ni) {
        int row = wn * 64 + ni * 16 + l16;
        bfr[ni] = *reinterpret_cast<const bf16x8*>(
            &Bl[row * 64 + (((kk * 4 + quad) ^ (row & 7)) * 8)]);
      }
#pragma unroll
      for (int mi = 0; mi < 4; ++mi)
#pragma unroll
        for (int ni = 0; ni < 4; ++ni)
          acc[mi][ni] = __builtin_amdgcn_mfma_f32_16x16x32_bf16(af[mi], bfr[ni], acc[mi][ni], 0, 0, 0);
    }
  }

#pragma unroll
  for (int mi = 0; mi < 4; ++mi)
#pragma unroll
    for (int ni = 0; ni < 4; ++ni)
#pragma unroll
      for (int r = 0; r < 4; ++r) {
        int row = m0 + wm * 64 + mi * 16 + quad * 4 + r;
        int col = n0 + wn * 64 + ni * 16 + l16;
        if (OUT_BF16)
          ((us*)Cv)[(size_t)row * N + col] = f2bf(acc[mi][ni][r]);
        else
          ((float*)Cv)[(size_t)row * N + col] = acc[mi][ni][r];
      }
}

// -------------------- V transpose: [t][d] -> [bh][d][T] --------------------
__global__ __launch_bounds__(256) void transpose_v(const us* __restrict__ QKV,
                                                   us* __restrict__ Vt) {
  __shared__ __align__(16) us lds[64 * 80];
  const int bid = blockIdx.x;
  const int kt = bid & 31;
  const int bh = bid >> 5;
  const int b = bh >> 4, h = bh & 15;
  const int tid = threadIdx.x;
#pragma unroll
  for (int it = 0; it < 2; ++it) {
    int u = it * 256 + tid;
    int j = u >> 3;
    int dc = (u & 7) * 8;
    uint4 raw = *reinterpret_cast<const uint4*>(
        &QKV[((size_t)(b * 2048 + kt * 64 + j)) * 3072 + 2048 + h * 64 + dc]);
    us tmp[8];
    *reinterpret_cast<uint4*>(tmp) = raw;
    int sj = (j & 15) * 4 + (j >> 4);
#pragma unroll
    for (int e = 0; e < 8; ++e) lds[(dc + e) * 80 + sj] = tmp[e];
  }
  __syncthreads();
  int d = tid >> 2, c = tid & 3;
  size_t orow = ((size_t)(bh * 64 + d)) * 2048 + kt * 64 + c * 16;
  *reinterpret_cast<uint4*>(&Vt[orow]) = *reinterpret_cast<const uint4*>(&lds[d * 80 + c * 16]);
  *reinterpret_cast<uint4*>(&Vt[orow + 8]) = *reinterpret_cast<const uint4*>(&lds[d * 80 + c * 16 + 8]);
}

// ---------------------------- flash attention ------------------------------
// 512 threads (8 waves), paired 128q tiles (p, 15-p); wave w owns rows
// q0 + w*16 + [0,16). p = exp2(s) via v_exp_f32; row sums accumulated on the
// MFMA pipe with a B-operand of ones (all 16 output cols identical).
__global__ __launch_bounds__(512, 4) void attn(
    const us* __restrict__ QKV, const us* __restrict__ Vt,
    us* __restrict__ O) {
  __shared__ __align__(16) us Kl[64 * 64];
  __shared__ __align__(16) us Vl[64 * 64];
  __shared__ __align__(16) us Pl[8][16 * 64];
  const int bid = blockIdx.x;
  const int pr = bid & 7;
  const int h = (bid >> 3) & 15;
  const int b = bid >> 7;
  const int q0A = pr * 128, q0B = (15 - pr) * 128;
  const int tid = threadIdx.x, lane = tid & 63, w = tid >> 6;
  const int quad = lane >> 4, l16 = lane & 15;
  const size_t rowbase = (size_t)b * 2048;
  const int qcol = h * 64;
  const int kcol = 1024 + h * 64;

  const bf16x8 ones = {(short)0x3F80, (short)0x3F80, (short)0x3F80, (short)0x3F80,
                       (short)0x3F80, (short)0x3F80, (short)0x3F80, (short)0x3F80};

  bf16x8 qfA[2], qfB[2];
#pragma unroll
  for (int dc = 0; dc < 2; ++dc) {
    qfA[dc] = *reinterpret_cast<const bf16x8*>(
        &QKV[(rowbase + q0A + w * 16 + l16) * 3072 + qcol + dc * 32 + quad * 8]);
    qfB[dc] = *reinterpret_cast<const bf16x8*>(
        &QKV[(rowbase + q0B + w * 16 + l16) * 3072 + qcol + dc * 32 + quad * 8]);
  }

  f32x4 oaccA[4] = {}, oaccB[4] = {};
  f32x4 laccA = {}, laccB = {};

  const int rr = tid >> 3;
  const int gu = (tid & 7) ^ (rr & 7);
  const int base = __builtin_amdgcn_readfirstlane(w * 512);
  const int nB = 2 * (15 - pr) + 2;

  auto process = [&](int q0, bf16x8 (&qf)[2], f32x4 (&oacc)[4],
                     f32x4& lacc, int kt) {
    f32x4 s[4] = {};
#pragma unroll
    for (int t = 0; t < 4; ++t) {
      int krow = t * 16 + l16;
#pragma unroll
      for (int dc = 0; dc < 2; ++dc) {
        bf16x8 kf = *reinterpret_cast<const bf16x8*>(
            &Kl[krow * 64 + (((dc * 4 + quad) ^ (l16 & 7)) * 8)]);
        s[t] = __builtin_amdgcn_mfma_f32_16x16x32_bf16(qf[dc], kf, s[t], 0, 0, 0);
      }
    }
    float p[4][4];
    bool do_mask = (kt * 64 + 63) > (q0 + w * 16);
    if (do_mask) {
#pragma unroll
      for (int t = 0; t < 4; ++t)
#pragma unroll
        for (int r = 0; r < 4; ++r) {
          float e = __builtin_amdgcn_exp2f(s[t][r]);
          int kg = kt * 64 + t * 16 + l16;
          int qgl = q0 + w * 16 + quad * 4 + r;
          p[t][r] = (kg <= qgl) ? e : 0.f;
        }
    } else {
#pragma unroll
      for (int t = 0; t < 4; ++t)
#pragma unroll
        for (int r = 0; r < 4; ++r)
          p[t][r] = __builtin_amdgcn_exp2f(s[t][r]);
    }
#pragma unroll
    for (int r = 0; r < 4; ++r) {
      int prow = quad * 4 + r;
      uint2 val;
      val.x = __builtin_amdgcn_perm(__float_as_uint(p[1][r]), __float_as_uint(p[0][r]), 0x07060302u);
      val.y = __builtin_amdgcn_perm(__float_as_uint(p[3][r]), __float_as_uint(p[2][r]), 0x07060302u);
      char* dst = (char*)&Pl[w][0] + prow * 128 +
                  (((l16 >> 1) ^ (prow & 7)) * 16) + (l16 & 1) * 8;
      *reinterpret_cast<uint2*>(dst) = val;
    }
    asm volatile("s_waitcnt lgkmcnt(0)" ::: "memory");  // wave-local P RAW
#pragma unroll
    for (int kc = 0; kc < 2; ++kc) {
      bf16x8 pf = *reinterpret_cast<const bf16x8*>(
          (const char*)&Pl[w][0] + l16 * 128 + (((kc * 4 + quad) ^ (l16 & 7)) * 16));
      lacc = __builtin_amdgcn_mfma_f32_16x16x32_bf16(pf, ones, lacc, 0, 0, 0);
#pragma unroll
      for (int dt = 0; dt < 4; ++dt) {
        bf16x8 vf = *reinterpret_cast<const bf16x8*>(
            &Vl[(dt * 16 + l16) * 64 + (((kc * 4 + quad) ^ (l16 & 7)) * 8)]);
        oacc[dt] = __builtin_amdgcn_mfma_f32_16x16x32_bf16(pf, vf, oacc[dt], 0, 0, 0);
      }
    }
  };

  for (int kt = 0; kt < nB; ++kt) {
    __syncthreads();
    GL2LDS16(QKV + (rowbase + kt * 64 + rr) * 3072 + kcol + gu * 8, &Kl[base]);
    GL2LDS16(Vt + ((size_t)((b * 16 + h) * 64 + rr)) * 2048 + kt * 64 + gu * 8, &Vl[base]);
    __syncthreads();
    if (kt * 64 <= q0B + w * 16 + 15) process(q0B, qfB, oaccB, laccB, kt);
    if (kt * 64 <= q0A + w * 16 + 15) process(q0A, qfA, oaccA, laccA, kt);
  }

  auto finalize = [&](int q0, f32x4 (&oacc)[4], f32x4& lacc) {
#pragma unroll
    for (int dt = 0; dt < 4; ++dt)
#pragma unroll
      for (int r = 0; r < 4; ++r) {
        int row = q0 + w * 16 + quad * 4 + r;
        O[(rowbase + row) * 1024 + qcol + dt * 16 + l16] = f2bf(oacc[dt][r] / lacc[r]);
      }
  };
  finalize(q0A, oaccA, laccA);
  finalize(q0B, oaccB, laccB);
}

// ------------------------------- launcher ----------------------------------
extern "C" void kernel_launch(void* const* d_in, const int* in_sizes, int n_in,
                              void* d_out, int out_size, void* d_ws, size_t ws_size,
                              hipStream_t stream) {
  const float* x = (const float*)d_in[0];
  const float* wq = (const float*)d_in[1];
  const float* wk = (const float*)d_in[2];
  const float* wv = (const float*)d_in[3];
  const float* wo = (const float*)d_in[4];

  const int BT = 8192, E = 1024;
  const size_t NX = (size_t)BT * E;
  const size_t NW = (size_t)E * E;

  us* xb = (us*)d_ws;                 // [8192][1024]; later reused as O
  us* wbuf = xb + NX;                 // wq|wk|wv|wo bf16
  us* QKV = wbuf + 4 * NW;            // [8192][3072]
  us* VtB = QKV + (size_t)BT * 3 * E; // [64 bh][64 d][2048]
  us* Ob = xb;

  cast_all<<<(int)((NX + 4 * NW) / 8 / 256), 256, 0, stream>>>(x, wq, wk, wv, wo, xb, wbuf);

  gemm_bt<1><<<dim3(24, 64), 256, 0, stream>>>(xb, wbuf, QKV, BT, 3 * E, E);
  transpose_v<<<64 * 32, 256, 0, stream>>>(QKV, VtB);
  attn<<<4 * 16 * 8, 512, 0, stream>>>(QKV, VtB, Ob);
  gemm_bt<0><<<dim3(8, 64), 256, 0, stream>>>(Ob, wbuf + 3 * NW, (float*)d_out, BT, E, E);
}